// Round 8
// baseline (303.942 us; speedup 1.0000x reference)
//
#include <hip/hip_runtime.h>
#include <hip/hip_bf16.h>
#include <cstdint>

#define NHEAD 8
#define HD 32
#define DM 256
#define HH 56
#define WWID 56
#define HW 3136          // 56*56
#define NB 2
#define NTOT (NB * HW)   // 6272 positions (batch folded into GEMM N)
#define SCALE 0.17677669529663687f   // 32^-0.5
#define NBLK 512
#define GEN0 0x13570000u
#define AGT __HIP_MEMORY_SCOPE_AGENT

typedef _Float16 f16;
typedef __attribute__((ext_vector_type(2))) _Float16 f16x2;
typedef __attribute__((ext_vector_type(8))) _Float16 f16x8;
typedef __attribute__((ext_vector_type(4))) float floatx4;

union U16 { uint4 u; f16x2 h2[4]; f16 h[8]; };

// ---------------------------------------------------------------------------
// 2-level grid barrier in global memory (d_ws). bar u32 layout:
//   [g*32] g=0..7 : group counters (64 blocks/group), 128B apart
//   [256]         : root counter (8 arrivals)
//   [288]         : generation (init GEN0 by block 0; +1 per barrier)
// Co-residency of all 512 blocks is unconditional (LDS 55KB/2blk, VGPR<=1024)
// so the spin cannot deadlock. threadfence = agent fence -> cross-XCD safe.
// ---------------------------------------------------------------------------
__device__ __forceinline__ void gridsync(unsigned* bar, unsigned expect) {
    __syncthreads();
    if (threadIdx.x == 0) {
        unsigned* gen = bar + 288;
        while (__hip_atomic_load(gen, __ATOMIC_ACQUIRE, AGT) != expect) {}
        __threadfence();   // make this block's prior writes device-visible
        unsigned* cg = bar + ((blockIdx.x >> 6) << 5);
        if (__hip_atomic_fetch_add(cg, 1u, __ATOMIC_ACQ_REL, AGT) == 63u) {
            __hip_atomic_store(cg, 0u, __ATOMIC_RELAXED, AGT);
            unsigned* root = bar + 256;
            if (__hip_atomic_fetch_add(root, 1u, __ATOMIC_ACQ_REL, AGT) == 7u) {
                __hip_atomic_store(root, 0u, __ATOMIC_RELAXED, AGT);
                __hip_atomic_store(gen, expect + 1u, __ATOMIC_RELEASE, AGT);
            } else {
                while (__hip_atomic_load(gen, __ATOMIC_ACQUIRE, AGT) == expect) {}
            }
        } else {
            while (__hip_atomic_load(gen, __ATOMIC_ACQUIRE, AGT) == expect) {}
        }
        __threadfence();   // acquire side: invalidate before reading others' data
    }
    __syncthreads();
}

// ---------------------------------------------------------------------------
// GEMM phase (grid-stride over tiles). A f16 [M][256] k-contig; B [NTOT][256]
// k-contig. BM=128, BN=64, BK=64, 4 waves, wave = 64x32 via 4x2 16x16x32_f16.
// MODE 0: M=768 fused qkv -> q/k/v f16 [b][h][p][d], q pre-scaled by SCALE.
// MODE 1: M=256 out-proj -> fp32 d_out [b][c][p].
// ---------------------------------------------------------------------------
template<int MODE>
__device__ __forceinline__ void gemm_phase(
    const f16* __restrict__ A, const f16* __restrict__ Bm,
    const float* __restrict__ b0, const float* __restrict__ b1,
    const float* __restrict__ b2,
    f16* __restrict__ o0, f16* __restrict__ o1, f16* __restrict__ o2,
    float* __restrict__ yo,
    void* smem, int ntiles)
{
    f16 (*As)[72] = (f16(*)[72])smem;                      // 18432 B
    f16 (*Bs)[72] = (f16(*)[72])((char*)smem + 18432);     //  9216 B
    const int t = threadIdx.x;
    const int wave = t >> 6, lane = t & 63;
    const int quad = lane >> 4, l16 = lane & 15;
    const int mw = (wave & 1) * 64, nw = (wave >> 1) * 32;
    const int srow = t >> 3, suc = (t & 7) << 3;

    for (int tile = blockIdx.x; tile < ntiles; tile += NBLK) {
        const int mt = tile / 98, nt = tile - mt * 98;
        const int n0g = nt * 64, m0 = mt * 128;
        const int bb = n0g / HW, np = n0g - bb * HW;       // never straddles
        const f16* Bb = Bm + (size_t)n0g * DM;
        floatx4 acc[4][2] = {};
        for (int k0 = 0; k0 < DM; k0 += 64) {
            #pragma unroll
            for (int pp = 0; pp < 4; ++pp) {
                const int row = srow + pp * 32;
                *(uint4*)&As[row][suc] =
                    *(const uint4*)&A[(size_t)(m0 + row) * DM + k0 + suc];
            }
            #pragma unroll
            for (int pp = 0; pp < 2; ++pp) {
                const int row = srow + pp * 32;
                *(uint4*)&Bs[row][suc] =
                    *(const uint4*)&Bb[(size_t)row * DM + k0 + suc];
            }
            __syncthreads();
            #pragma unroll
            for (int ks = 0; ks < 2; ++ks) {
                f16x8 af[4], bf[2];
                #pragma unroll
                for (int mt2 = 0; mt2 < 4; ++mt2)
                    af[mt2] = *(const f16x8*)&As[mw + mt2 * 16 + l16][ks * 32 + quad * 8];
                #pragma unroll
                for (int nt2 = 0; nt2 < 2; ++nt2)
                    bf[nt2] = *(const f16x8*)&Bs[nw + nt2 * 16 + l16][ks * 32 + quad * 8];
                #pragma unroll
                for (int mt2 = 0; mt2 < 4; ++mt2)
                    #pragma unroll
                    for (int nt2 = 0; nt2 < 2; ++nt2)
                        acc[mt2][nt2] = __builtin_amdgcn_mfma_f32_16x16x32_f16(
                            af[mt2], bf[nt2], acc[mt2][nt2], 0, 0, 0);
            }
            __syncthreads();
        }
        if (MODE == 0) {
            #pragma unroll
            for (int mt2 = 0; mt2 < 4; ++mt2) {
                const int gm = m0 + mw + mt2 * 16 + quad * 4;
                const int proj = gm >> 8;
                const int c = gm & 255;
                const int h = c >> 5, d0 = c & 31;
                const float* bptr = proj == 0 ? b0 : (proj == 1 ? b1 : b2);
                f16* op = proj == 0 ? o0 : (proj == 1 ? o1 : o2);
                const float sc = proj == 0 ? SCALE : 1.0f;
                const size_t base = ((size_t)(bb * NHEAD + h) * HW) * HD + d0;
                float bias[4] = {bptr[c], bptr[c + 1], bptr[c + 2], bptr[c + 3]};
                #pragma unroll
                for (int nt2 = 0; nt2 < 2; ++nt2) {
                    const int p = np + nw + nt2 * 16 + l16;
                    union { ushort4 u; f16 h[4]; } pk;
                    #pragma unroll
                    for (int r = 0; r < 4; ++r)
                        pk.h[r] = (f16)((acc[mt2][nt2][r] + bias[r]) * sc);
                    *(ushort4*)&op[base + (size_t)p * HD] = pk.u;
                }
            }
        } else {
            #pragma unroll
            for (int mt2 = 0; mt2 < 4; ++mt2) {
                const int gc = m0 + mw + mt2 * 16 + quad * 4;
                #pragma unroll
                for (int r = 0; r < 4; ++r) {
                    const float bias = b0[gc + r];
                    #pragma unroll
                    for (int nt2 = 0; nt2 < 2; ++nt2) {
                        const int p = np + nw + nt2 * 16 + l16;
                        yo[(size_t)(bb * DM + gc + r) * HW + p] = acc[mt2][nt2][r] + bias;
                    }
                }
            }
        }
    }
}

// ---------------------------------------------------------------------------
// Fused persistent kernel: prep -> qkv GEMM -> window attention -> out GEMM,
// separated by 3 grid barriers. 512 blocks x 256 threads, 27.6 KB LDS arena.
// ---------------------------------------------------------------------------
__global__ __launch_bounds__(256) void fused_all(
    const float* __restrict__ x,
    const float* __restrict__ wq, const float* __restrict__ bq,
    const float* __restrict__ wk, const float* __restrict__ bk,
    const float* __restrict__ wv, const float* __restrict__ bv,
    const float* __restrict__ wo, const float* __restrict__ bo,
    f16* __restrict__ xT, f16* __restrict__ wcat, f16* __restrict__ wob,
    f16* __restrict__ qb, f16* __restrict__ kb, f16* __restrict__ vb,
    f16* __restrict__ attnT, float* __restrict__ out, unsigned* bar)
{
    __shared__ __align__(16) unsigned char smem[27648];
    const int bid = blockIdx.x, t = threadIdx.x;

    if (bid == 0 && t == 0) {      // barrier init (d_ws poisoned 0xAA each call)
        #pragma unroll
        for (int g = 0; g < 8; ++g)
            __hip_atomic_store(bar + g * 32, 0u, __ATOMIC_RELAXED, AGT);
        __hip_atomic_store(bar + 256, 0u, __ATOMIC_RELAXED, AGT);
        __hip_atomic_store(bar + 288, GEN0, __ATOMIC_RELEASE, AGT);
    }

    // ---------------- P0: x transpose (392 blocks) + weight convert (120) ---
    if (bid < 392) {
        float (*tile)[65] = (float(*)[65])smem;
        const int b = bid / 196, r = bid - b * 196;   // 4 c-tiles x 49 p-tiles
        const int ct = r / 49, pt = r - ct * 49;
        const int p0 = pt * 64, c0 = ct * 64;
        const float* xb = x + (size_t)b * DM * HW;
        #pragma unroll
        for (int i = 0; i < 4; ++i) {
            const int u = t + i * 256;
            const int rc = u >> 4, p4 = (u & 15) << 2;
            *(float4*)&tile[rc][p4] =
                *(const float4*)&xb[(size_t)(c0 + rc) * HW + p0 + p4];
        }
        __syncthreads();
        f16* xo = xT + (size_t)b * HW * DM;
        #pragma unroll
        for (int i = 0; i < 2; ++i) {
            const int u = t + i * 256;
            const int ch = u & 7, pq = u >> 3;
            U16 pk;
            #pragma unroll
            for (int kk = 0; kk < 8; ++kk)       // stride-65: conflict-free
                pk.h[kk] = (f16)tile[ch * 8 + kk][pq];
            *(uint4*)&xo[(size_t)(p0 + pq) * DM + c0 + ch * 8] = pk.u;
        }
    } else {
        for (int gid = (bid - 392) * 256 + t; gid < 65536; gid += 30720) {
            const int idx4 = gid << 2;
            const int sel = idx4 >> 16, off = idx4 & 65535;
            const float* src = sel == 0 ? wq : (sel == 1 ? wk : (sel == 2 ? wv : wo));
            f16* dst = sel < 3 ? (wcat + (sel << 16) + off) : (wob + off);
            float4 f = *(const float4*)&src[off];
            union { ushort4 u; f16 h[4]; } pk;
            pk.h[0] = (f16)f.x; pk.h[1] = (f16)f.y;
            pk.h[2] = (f16)f.z; pk.h[3] = (f16)f.w;
            *(ushort4*)dst = pk.u;
        }
    }
    gridsync(bar, GEN0);

    // ---------------- P1: fused qkv GEMM (588 tiles) ------------------------
    gemm_phase<0>(wcat, xT, bq, bk, bv, qb, kb, vb, nullptr, smem, 588);
    gridsync(bar, GEN0 + 1);

    // ---------------- P2: window attention, 8x8 tiles (784) -----------------
    // 256 thr = 64 pos x 4 chunk-lanes; 14x14 zero-padded halo in LDS.
    // OOB slots are true zeros -> score 0 -> exp(0)=1 joins the denominator
    // automatically (exact reference semantics, no validity predicate).
    {
        uint4* kh = (uint4*)smem;                       // 784 x 16B
        uint4* vh = (uint4*)(smem + 12544);             // 784 x 16B
        for (int tl = bid; tl < 784; tl += NBLK) {
            const int bh = tl / 49, r = tl - bh * 49;
            const int ry = r / 7;
            const int ty0 = ry * 8, tx0 = (r - ry * 7) * 8;
            const f16* kp = kb + (size_t)bh * HW * HD;
            const f16* vp = vb + (size_t)bh * HW * HD;
            __syncthreads();
            for (int u = t; u < 784; u += 256) {
                const int pos = u >> 2, ch = u & 3;
                const int hy = pos / 14, hx = pos - hy * 14;
                const int gy = ty0 + hy - 3, gx = tx0 + hx - 3;
                uint4 kv = make_uint4(0, 0, 0, 0), vv = make_uint4(0, 0, 0, 0);
                if ((unsigned)gy < HH && (unsigned)gx < WWID) {
                    const size_t g = (size_t)(gy * WWID + gx) * HD + (ch << 3);
                    kv = *(const uint4*)&kp[g];
                    vv = *(const uint4*)&vp[g];
                }
                kh[u] = kv; vh[u] = vv;
            }
            __syncthreads();
            const int pl = t >> 2, ch = t & 3;
            const int ty = pl >> 3, tx = pl & 7;
            const int p = (ty0 + ty) * WWID + tx0 + tx;
            U16 qu;
            qu.u = *(const uint4*)(qb + (size_t)bh * HW * HD + (size_t)p * HD + (ch << 3));
            const uint4* kbase = kh + (ty * 14 + tx) * 4 + ch;
            const uint4* vbase = vh + (ty * 14 + tx) * 4 + ch;
            float of[8] = {};
            float sum = 0.f;
            for (int i = 0; i < 7; ++i) {
                #pragma unroll
                for (int j = 0; j < 7; ++j) {
                    const int off = (i * 14 + j) << 2;
                    U16 ku; ku.u = kbase[off];
                    float s = __builtin_amdgcn_fdot2(ku.h2[0], qu.h2[0], 0.0f, false);
                    s = __builtin_amdgcn_fdot2(ku.h2[1], qu.h2[1], s, false);
                    s = __builtin_amdgcn_fdot2(ku.h2[2], qu.h2[2], s, false);
                    s = __builtin_amdgcn_fdot2(ku.h2[3], qu.h2[3], s, false);
                    s += __shfl_xor(s, 1);
                    s += __shfl_xor(s, 2);
                    const float e = __expf(s);
                    sum += e;
                    U16 vu; vu.u = vbase[off];
                    of[0] = fmaf((float)vu.h[0], e, of[0]);
                    of[1] = fmaf((float)vu.h[1], e, of[1]);
                    of[2] = fmaf((float)vu.h[2], e, of[2]);
                    of[3] = fmaf((float)vu.h[3], e, of[3]);
                    of[4] = fmaf((float)vu.h[4], e, of[4]);
                    of[5] = fmaf((float)vu.h[5], e, of[5]);
                    of[6] = fmaf((float)vu.h[6], e, of[6]);
                    of[7] = fmaf((float)vu.h[7], e, of[7]);
                }
            }
            const float inv = 1.0f / sum;
            f16* op = attnT + ((size_t)(bh >> 3) * HW + p) * DM
                            + (bh & 7) * HD + (ch << 3);
            U16 ou;
            #pragma unroll
            for (int j = 0; j < 8; ++j)
                ou.h[j] = (f16)(of[j] * inv);
            *(uint4*)op = ou.u;
        }
    }
    gridsync(bar, GEN0 + 2);

    // ---------------- P3: out projection (196 tiles) ------------------------
    gemm_phase<1>(wob, attnT, bo, nullptr, nullptr,
                  nullptr, nullptr, nullptr, out, smem, 196);
}

// ---------------------------------------------------------------------------
extern "C" void kernel_launch(void* const* d_in, const int* in_sizes, int n_in,
                              void* d_out, int out_size, void* d_ws, size_t ws_size,
                              hipStream_t stream) {
    const float* x  = (const float*)d_in[0];
    const float* wq = (const float*)d_in[1];
    const float* bq = (const float*)d_in[2];
    const float* wk = (const float*)d_in[3];
    const float* bk = (const float*)d_in[4];
    const float* wv = (const float*)d_in[5];
    const float* bv = (const float*)d_in[6];
    const float* wo = (const float*)d_in[7];
    const float* bo = (const float*)d_in[8];
    float* out = (float*)d_out;

    const size_t NPC = (size_t)NTOT * DM;
    f16* xT    = (f16*)d_ws;               // [b][p][c]
    f16* wcat  = xT + NPC;                 // [768][256]
    f16* wob   = wcat + 768 * 256;         // [256][256]
    f16* qb    = wob + 256 * 256;          // [b][h][p][d], q pre-scaled
    f16* kb    = qb + NPC;
    f16* vb    = kb + NPC;
    f16* attnT = vb + NPC;                 // [b][p][c]
    unsigned* bar = (unsigned*)(attnT + NPC);

    fused_all<<<NBLK, 256, 0, stream>>>(
        x, wq, bq, wk, bk, wv, bv, wo, bo,
        xT, wcat, wob, qb, kb, vb, attnT, out, bar);
}

// Round 9
// 112.833 us; speedup vs baseline: 2.6937x; 2.6937x over previous
//
#include <hip/hip_runtime.h>
#include <hip/hip_bf16.h>
#include <cstdint>

#define NHEAD 8
#define HD 32
#define DM 256
#define HH 56
#define WWID 56
#define HW 3136          // 56*56
#define NB 2
#define NTOT (NB * HW)   // 6272 positions (batch folded into GEMM N)
#define SCALE 0.17677669529663687f   // 32^-0.5

typedef _Float16 f16;
typedef __attribute__((ext_vector_type(2))) _Float16 f16x2;
typedef __attribute__((ext_vector_type(8))) _Float16 f16x8;
typedef __attribute__((ext_vector_type(4))) float floatx4;

union U16 { uint4 u; f16x2 h2[4]; f16 h[8]; };

// ---------------------------------------------------------------------------
// qkv GEMM, fp32 inputs converted in-staging (no prep kernel, no xT buffer).
// Grid (98, 6): y -> proj (y>>1) and m-half (y&1). BM=128, BN=64, BK=64,
// 4 waves, wave = 64x32 via 4x2 tiles of 16x16x32_f16.
// A: w fp32 [256][256] row-major -> f16 As (2 float4 + cvt per chunk).
// B: x fp32 [b][c][p] -> TRANSPOSED f16 Bs[n][k]: lane-spread scalar loads
//    (rows t&15 + 16i -> 4x64B segments/wave) + scalar b16 LDS writes
//    (stride-72 rows: 16 banks x 4-way, ~1.58x — bounded).
// Epilogue -> q/k/v f16 [b][h][p][d]; q pre-scaled by SCALE.
// ---------------------------------------------------------------------------
__global__ __launch_bounds__(256) void gemm_qkv(
    const float* __restrict__ x,
    const float* __restrict__ wq, const float* __restrict__ bq,
    const float* __restrict__ wk, const float* __restrict__ bk,
    const float* __restrict__ wv, const float* __restrict__ bv,
    f16* __restrict__ qo, f16* __restrict__ ko, f16* __restrict__ vo)
{
    const int n0g = blockIdx.x * 64;
    const int ym  = blockIdx.y;
    const int proj = ym >> 1;
    const int mloc = (ym & 1) * 128;
    const int bb = n0g / HW, np = n0g - bb * HW;   // tile never straddles batch
    const float* __restrict__ w  = proj == 0 ? wq : (proj == 1 ? wk : wv);
    const float* __restrict__ bi = proj == 0 ? bq : (proj == 1 ? bk : bv);
    f16* __restrict__ o = proj == 0 ? qo : (proj == 1 ? ko : vo);
    const float sc = proj == 0 ? SCALE : 1.0f;
    const float* xb = x + (size_t)bb * DM * HW;

    __shared__ __align__(16) f16 As[128][72];
    __shared__ __align__(16) f16 Bs[64][72];

    const int t = threadIdx.x;
    const int wave = t >> 6, lane = t & 63;
    const int quad = lane >> 4, l16 = lane & 15;
    const int mw = (wave & 1) * 64, nw = (wave >> 1) * 32;

    floatx4 acc[4][2] = {};

    const int srow = t >> 3, suc = (t & 7) << 3;   // A staging map
    const int bc = t >> 4, bp = t & 15;            // B staging map

    for (int k0 = 0; k0 < DM; k0 += 64) {
        #pragma unroll
        for (int pp = 0; pp < 4; ++pp) {           // A: fp32 -> f16
            const int row = srow + pp * 32;
            const float* wr = &w[(size_t)(mloc + row) * DM + k0 + suc];
            float4 a0 = *(const float4*)wr;
            float4 a1 = *(const float4*)(wr + 4);
            U16 pk;
            pk.h[0] = (f16)a0.x; pk.h[1] = (f16)a0.y;
            pk.h[2] = (f16)a0.z; pk.h[3] = (f16)a0.w;
            pk.h[4] = (f16)a1.x; pk.h[5] = (f16)a1.y;
            pk.h[6] = (f16)a1.z; pk.h[7] = (f16)a1.w;
            *(uint4*)&As[row][suc] = pk.u;
        }
        #pragma unroll
        for (int pp = 0; pp < 4; ++pp) {           // B: transpose in-staging
            const int cl = pp * 16 + bc;           // 0..63
            const float* xr = &xb[(size_t)(k0 + cl) * HW + np + bp];
            #pragma unroll
            for (int i = 0; i < 4; ++i)
                Bs[bp + 16 * i][cl] = (f16)xr[16 * i];
        }
        __syncthreads();
        #pragma unroll
        for (int ks = 0; ks < 2; ++ks) {
            f16x8 af[4], bf[2];
            #pragma unroll
            for (int mt = 0; mt < 4; ++mt)
                af[mt] = *(const f16x8*)&As[mw + mt * 16 + l16][ks * 32 + quad * 8];
            #pragma unroll
            for (int nt = 0; nt < 2; ++nt)
                bf[nt] = *(const f16x8*)&Bs[nw + nt * 16 + l16][ks * 32 + quad * 8];
            #pragma unroll
            for (int mt = 0; mt < 4; ++mt)
                #pragma unroll
                for (int nt = 0; nt < 2; ++nt)
                    acc[mt][nt] = __builtin_amdgcn_mfma_f32_16x16x32_f16(
                        af[mt], bf[nt], acc[mt][nt], 0, 0, 0);
        }
        __syncthreads();
    }

    #pragma unroll
    for (int mt = 0; mt < 4; ++mt) {
        const int c = mloc + mw + mt * 16 + quad * 4;   // out channel 0..255
        const int h = c >> 5, d0 = c & 31;
        const size_t base = ((size_t)(bb * NHEAD + h) * HW) * HD + d0;
        float bias[4] = {bi[c], bi[c + 1], bi[c + 2], bi[c + 3]};
        #pragma unroll
        for (int nt = 0; nt < 2; ++nt) {
            const int p = np + nw + nt * 16 + l16;
            union { ushort4 u; f16 h[4]; } pk;
            #pragma unroll
            for (int r = 0; r < 4; ++r)
                pk.h[r] = (f16)((acc[mt][nt][r] + bias[r]) * sc);
            *(ushort4*)&o[base + (size_t)p * HD] = pk.u;
        }
    }
}

// ---------------------------------------------------------------------------
// out projection: A = wo fp32 converted in-staging; B = attnT f16 [p][c]
// k-contig (vectorized staging). Grid (98, 2). fp32 out [b][c][p].
// ---------------------------------------------------------------------------
__global__ __launch_bounds__(256) void gemm_out(
    const f16* __restrict__ Bm, const float* __restrict__ wo,
    const float* __restrict__ bo, float* __restrict__ yo)
{
    const int n0g = blockIdx.x * 64;
    const int m0 = blockIdx.y * 128;
    const int bb = n0g / HW, np = n0g - bb * HW;
    const f16* Bb = Bm + (size_t)n0g * DM;

    __shared__ __align__(16) f16 As[128][72];
    __shared__ __align__(16) f16 Bs[64][72];

    const int t = threadIdx.x;
    const int wave = t >> 6, lane = t & 63;
    const int quad = lane >> 4, l16 = lane & 15;
    const int mw = (wave & 1) * 64, nw = (wave >> 1) * 32;

    floatx4 acc[4][2] = {};
    const int srow = t >> 3, suc = (t & 7) << 3;

    for (int k0 = 0; k0 < DM; k0 += 64) {
        #pragma unroll
        for (int pp = 0; pp < 4; ++pp) {           // A: wo fp32 -> f16
            const int row = srow + pp * 32;
            const float* wr = &wo[(size_t)(m0 + row) * DM + k0 + suc];
            float4 a0 = *(const float4*)wr;
            float4 a1 = *(const float4*)(wr + 4);
            U16 pk;
            pk.h[0] = (f16)a0.x; pk.h[1] = (f16)a0.y;
            pk.h[2] = (f16)a0.z; pk.h[3] = (f16)a0.w;
            pk.h[4] = (f16)a1.x; pk.h[5] = (f16)a1.y;
            pk.h[6] = (f16)a1.z; pk.h[7] = (f16)a1.w;
            *(uint4*)&As[row][suc] = pk.u;
        }
        #pragma unroll
        for (int pp = 0; pp < 2; ++pp) {           // B: f16, vectorized
            const int row = srow + pp * 32;
            *(uint4*)&Bs[row][suc] =
                *(const uint4*)&Bb[(size_t)row * DM + k0 + suc];
        }
        __syncthreads();
        #pragma unroll
        for (int ks = 0; ks < 2; ++ks) {
            f16x8 af[4], bf[2];
            #pragma unroll
            for (int mt = 0; mt < 4; ++mt)
                af[mt] = *(const f16x8*)&As[mw + mt * 16 + l16][ks * 32 + quad * 8];
            #pragma unroll
            for (int nt = 0; nt < 2; ++nt)
                bf[nt] = *(const f16x8*)&Bs[nw + nt * 16 + l16][ks * 32 + quad * 8];
            #pragma unroll
            for (int mt = 0; mt < 4; ++mt)
                #pragma unroll
                for (int nt = 0; nt < 2; ++nt)
                    acc[mt][nt] = __builtin_amdgcn_mfma_f32_16x16x32_f16(
                        af[mt], bf[nt], acc[mt][nt], 0, 0, 0);
        }
        __syncthreads();
    }

    #pragma unroll
    for (int mt = 0; mt < 4; ++mt) {
        const int gc = m0 + mw + mt * 16 + quad * 4;
        #pragma unroll
        for (int r = 0; r < 4; ++r) {
            const float bias = bo[gc + r];
            #pragma unroll
            for (int nt = 0; nt < 2; ++nt) {
                const int p = np + nw + nt * 16 + l16;
                yo[(size_t)(bb * DM + gc + r) * HW + p] = acc[mt][nt][r] + bias;
            }
        }
    }
}

// ---------------------------------------------------------------------------
// Sliding-window attention — unchanged from R6/R7 (proven, no spills).
// d-split: 448 thr = 112 positions (2 rows x 56) x 4 chunk-lanes.
// f16: K score via v_dot2_f32_f16, V accum via fma_mix, q pre-scaled.
// LDS halo [pos'][chunk] uint4 -> wave reads contiguous 1KB, conflict-free.
// Zero-pad: y-OOB rows + guards zeroed; x-invalid adds exp(0)=1 to denom.
// ---------------------------------------------------------------------------
#define HROWS 8                    // 2 + 6 halo
#define HPOS  (HROWS * WWID)       // 448
#define HPP   (HPOS + 6)           // 454: +3 guard positions each side

__global__ __launch_bounds__(448) void attn_win(
    const f16* __restrict__ q,
    const f16* __restrict__ k,
    const f16* __restrict__ v,
    f16* __restrict__ out)
{
    __shared__ uint4 kh[HPP * 4];   // 29,056 B
    __shared__ uint4 vh[HPP * 4];   // 29,056 B

    const int t = threadIdx.x;            // 0..447
    const int tile = blockIdx.x;          // 0..27
    const int h = blockIdx.y, b = blockIdx.z;
    const int y0 = tile * 2;
    const size_t base = (size_t)(b * NHEAD + h) * HW * HD;
    const f16* kp = k + base;
    const f16* vp = v + base;

    #pragma unroll
    for (int it = 0; it < 4; ++it) {      // stage halo rows y0-3 .. y0+4
        const int u = t + it * 448;
        const int pos = u >> 2, ch = u & 3;
        const int hr = pos / WWID;
        const int gx = pos - hr * WWID;
        const int gy = y0 - 3 + hr;
        uint4 kv = make_uint4(0, 0, 0, 0), vv = make_uint4(0, 0, 0, 0);
        if ((unsigned)gy < HH) {
            const size_t g = (size_t)(gy * WWID + gx) * HD + (ch << 3);
            kv = *(const uint4*)&kp[g];
            vv = *(const uint4*)&vp[g];
        }
        kh[u + 12] = kv;
        vh[u + 12] = vv;
    }
    if (t < 48) {   // zero guards: 3 low + 3 high positions x 4 chunks
        const int ps = t % 6;
        const int fi = (ps < 3 ? ps * 4 : (HPOS + ps) * 4) + ((t / 6) & 3);
        const uint4 z = make_uint4(0, 0, 0, 0);
        if (t < 24) kh[fi] = z; else vh[fi] = z;
    }
    __syncthreads();

    const int pl = t >> 2;                // local position 0..111
    const int ch = t & 3;                 // chunk 0..3
    const int lx = pl >= WWID ? pl - WWID : pl;
    const int p = y0 * WWID + pl;

    U16 qu;                               // my q chunk (pre-scaled by SCALE)
    qu.u = *(const uint4*)(q + base + (size_t)p * HD + (ch << 3));

    const uint4* kb4 = kh + t;
    const uint4* vb4 = vh + t;

    float of[8] = {};
    float sum = 0.f;
    for (int i = 0; i < 7; ++i) {
        #pragma unroll
        for (int j = 0; j < 7; ++j) {
            const int off4 = (i * WWID + j) << 2;
            U16 ku; ku.u = kb4[off4];
            float s;
            s = __builtin_amdgcn_fdot2(ku.h2[0], qu.h2[0], 0.0f, false);
            s = __builtin_amdgcn_fdot2(ku.h2[1], qu.h2[1], s, false);
            s = __builtin_amdgcn_fdot2(ku.h2[2], qu.h2[2], s, false);
            s = __builtin_amdgcn_fdot2(ku.h2[3], qu.h2[3], s, false);
            s += __shfl_xor(s, 1);
            s += __shfl_xor(s, 2);
            const bool xv = (unsigned)(lx + j - 3) < WWID;
            const float e = __expf(s);
            sum += xv ? e : 1.0f;
            const float wt = xv ? e : 0.0f;
            U16 vu; vu.u = vb4[off4];
            of[0] = fmaf((float)vu.h[0], wt, of[0]);
            of[1] = fmaf((float)vu.h[1], wt, of[1]);
            of[2] = fmaf((float)vu.h[2], wt, of[2]);
            of[3] = fmaf((float)vu.h[3], wt, of[3]);
            of[4] = fmaf((float)vu.h[4], wt, of[4]);
            of[5] = fmaf((float)vu.h[5], wt, of[5]);
            of[6] = fmaf((float)vu.h[6], wt, of[6]);
            of[7] = fmaf((float)vu.h[7], wt, of[7]);
        }
    }

    const float inv = 1.0f / sum;
    f16* op = out + ((size_t)b * HW + p) * DM + h * HD + (ch << 3);
    U16 ou;
    #pragma unroll
    for (int j = 0; j < 8; ++j)
        ou.h[j] = (f16)(of[j] * inv);
    *(uint4*)op = ou.u;
}

// ---------------------------------------------------------------------------
extern "C" void kernel_launch(void* const* d_in, const int* in_sizes, int n_in,
                              void* d_out, int out_size, void* d_ws, size_t ws_size,
                              hipStream_t stream) {
    const float* x  = (const float*)d_in[0];
    const float* wq = (const float*)d_in[1];
    const float* bq = (const float*)d_in[2];
    const float* wk = (const float*)d_in[3];
    const float* bk = (const float*)d_in[4];
    const float* wv = (const float*)d_in[5];
    const float* bv = (const float*)d_in[6];
    const float* wo = (const float*)d_in[7];
    const float* bo = (const float*)d_in[8];
    float* out = (float*)d_out;

    const size_t NPC = (size_t)NTOT * DM;
    f16* qb    = (f16*)d_ws;               // [b][h][p][d], q pre-scaled
    f16* kb    = qb + NPC;
    f16* vb    = kb + NPC;
    f16* attnT = vb + NPC;                 // [b][p][c]

    gemm_qkv<<<dim3(NTOT / 64, 6), 256, 0, stream>>>(
        x, wq, bq, wk, bk, wv, bv, qb, kb, vb);
    attn_win<<<dim3(28, NHEAD, NB), 448, 0, stream>>>(qb, kb, vb, attnT);
    gemm_out<<<dim3(NTOT / 64, 2), 256, 0, stream>>>(attnT, wo, bo, out);
}